// Round 11
// baseline (1500.189 us; speedup 1.0000x reference)
//
#include <hip/hip_runtime.h>
#include <hip/hip_bf16.h>
#include <float.h>

#define N_NODES 50000
#define N_EDGES 800000
#define D_H 128
#define N_GRAPHS 512
#define EPSV 1e-5f
#define NB_SCAN ((N_NODES + 255) / 256)   // 196

// ---------------- atomic float max (bit trick) ----------------
__device__ __forceinline__ void atomicMaxF(float* addr, float val) {
    if (val >= 0.0f) atomicMax((int*)addr, __float_as_int(val));
    else atomicMin((unsigned int*)addr, (unsigned int)__float_as_int(val));
}

// ---------------- CSR build ----------------
__global__ void hist_kernel(const int* __restrict__ dst, int* __restrict__ cnt) {
    int e = blockIdx.x * blockDim.x + threadIdx.x;
    if (e < N_EDGES) atomicAdd(&cnt[dst[e]], 1);
}

__global__ __launch_bounds__(256) void scan_local_kernel(const int* __restrict__ cnt,
                                                         int* __restrict__ row_ptr,
                                                         int* __restrict__ bsum) {
    __shared__ int sh[256];
    int t = threadIdx.x;
    int i = blockIdx.x * 256 + t;
    int v = (i < N_NODES) ? cnt[i] : 0;
    sh[t] = v;
    __syncthreads();
    int x = v;
    for (int off = 1; off < 256; off <<= 1) {
        int y = (t >= off) ? sh[t - off] : 0;
        __syncthreads();
        x += y;
        sh[t] = x;
        __syncthreads();
    }
    if (i < N_NODES) row_ptr[i] = x - v;   // local exclusive
    if (t == 255) bsum[blockIdx.x] = x;
}

// add block offsets (each block reduces bsum itself); init pools + row_ptr[N]
__global__ __launch_bounds__(256) void scan_add_kernel(int* __restrict__ row_ptr,
                                                       int* __restrict__ wofs,
                                                       const int* __restrict__ bsum,
                                                       float* __restrict__ psum,
                                                       float* __restrict__ pcnt,
                                                       float* __restrict__ pmax) {
    __shared__ int sh[256];
    int t = threadIdx.x;
    int v = (t < NB_SCAN && t < blockIdx.x) ? bsum[t] : 0;
    sh[t] = v;
    __syncthreads();
    for (int off = 128; off; off >>= 1) {
        if (t < off) sh[t] += sh[t + off];
        __syncthreads();
    }
    int bofs = sh[0];
    int i = blockIdx.x * 256 + t;
    if (i < N_NODES) {
        int r = row_ptr[i] + bofs;
        row_ptr[i] = r;
        wofs[i] = r;
    }
    if (i == 0) row_ptr[N_NODES] = N_EDGES;
    if (i < N_GRAPHS * 2) { psum[i] = 0.f; pmax[i] = -FLT_MAX; }
    if (i < N_GRAPHS) pcnt[i] = 0.f;
}

__global__ void scatter_kernel(const int* __restrict__ src, const int* __restrict__ dst,
                               int* __restrict__ wofs, int* __restrict__ csr_src) {
    int e = blockIdx.x * blockDim.x + threadIdx.x;
    if (e < N_EDGES) {
        int pos = atomicAdd(&wofs[dst[e]], 1);
        csr_src[pos] = src[e];
    }
}

// ---------------- fused SAGE layer: pipelined gather + GEMM + BN + ReLU -------
// 4 waves/block of 256; wave owns RPW=8 rows end-to-end; s_agg rows wave-private
// -> NO barrier. LDS = s_agg only (16KB): the GEMM's root-row (x) reads are
// wave-uniform -> read from global via SGPR-held pointers (scalar-cache path),
// so s_x is unnecessary. Gather: wave's contiguous edge range streamed with a
// SPLIT pipeline — idx loads run 2 chunks ahead, row loads 1 chunk ahead, so
// the 16 in-flight loads never serialize idx->row within a chunk.
// launch_bounds(256,6): 85-VGPR budget (body ~64-80), 6 blocks/CU -> grid
// (1563 blocks) ~fully resident.
#define ROWS 32
#define RPW 8   // rows per wave
template <int MODE>
__global__ __launch_bounds__(256, 6) void fused_sage_kernel(
    const float* __restrict__ xin,
    const int* __restrict__ row_ptr, const int* __restrict__ csr_src,
    const float* __restrict__ Wl, const float* __restrict__ bl,
    const float* __restrict__ Wr,
    const float* __restrict__ gg, const float* __restrict__ bb,
    const float* __restrict__ mm, const float* __restrict__ vv,
    float* __restrict__ hout,
    const float* __restrict__ Wl2, const float* __restrict__ Wr2,
    float* __restrict__ p2r2) {
    __shared__ float s_agg[ROWS][D_H];
    int row0 = blockIdx.x * ROWS;
    int t = threadIdx.x;
    int lane = t & 63;
    int w = t >> 6;   // wave id 0..3

    const float2* xp = (const float2*)xin;

    // pipelined gather over the wave's contiguous edge range
    int rbeg = row0 + w * RPW;
    int rwend = rbeg + RPW; if (rwend > N_NODES) rwend = N_NODES;
    if (rbeg < N_NODES) {
        int E0 = row_ptr[rbeg];
        int E1 = row_ptr[rwend];
        int cur = rbeg;
        int cur_start = E0;
        int cur_end = row_ptr[cur + 1];
        float ax = 0.f, ay = 0.f;

        int iA[8], iB[8];
        float2 vA[8], vB[8];

        auto idxLoad = [&](int* I, int cbase) {
#pragma unroll
            for (int k = 0; k < 8; k++) {
                int e = cbase + k;
                I[k] = csr_src[(e < E1) ? e : (E1 - 1)];
            }
        };
        auto rowLoad = [&](float2* V, const int* I) {
#pragma unroll
            for (int k = 0; k < 8; k++) V[k] = xp[(size_t)I[k] * 64 + lane];
        };
        auto consume = [&](const float2* V, int cbase) {
#pragma unroll
            for (int k = 0; k < 8; k++) {
                int epos = cbase + k;
                if (epos < E1) {
                    while (epos >= cur_end) {   // finalize rows (handles empties)
                        float inv = 1.0f / (float)max(cur_end - cur_start, 1);
                        ((float2*)s_agg[cur - row0])[lane] =
                            make_float2(ax * inv, ay * inv);
                        ax = 0.f; ay = 0.f;
                        cur++;
                        cur_start = cur_end;
                        cur_end = row_ptr[cur + 1];
                    }
                    ax += V[k].x;
                    ay += V[k].y;
                }
            }
        };

        int nchunks = (E1 - E0 + 7) >> 3;
        if (nchunks > 0) {
            idxLoad(iA, E0);          // chunk 0 idx
            rowLoad(vA, iA);          // chunk 0 rows (one idx-wait, prologue only)
            if (nchunks > 1) idxLoad(iB, E0 + 8);   // chunk 1 idx in flight
            for (int c = 0; c < nchunks; c++) {
                int base = E0 + c * 8;
                if ((c & 1) == 0) {
                    if (c + 1 < nchunks) rowLoad(vB, iB);            // rows c+1
                    if (c + 2 < nchunks) idxLoad(iA, base + 16);     // idx c+2
                    consume(vA, base);                               // chunk c
                } else {
                    if (c + 1 < nchunks) rowLoad(vA, iA);
                    if (c + 2 < nchunks) idxLoad(iB, base + 16);
                    consume(vB, base);
                }
            }
        }
        // drain remaining rows (partial current + trailing empties)
        while (cur < rwend) {
            float inv = 1.0f / (float)max(cur_end - cur_start, 1);
            ((float2*)s_agg[cur - row0])[lane] = make_float2(ax * inv, ay * inv);
            ax = 0.f; ay = 0.f;
            cur++;
            if (cur < rwend) { cur_start = cur_end; cur_end = row_ptr[cur + 1]; }
        }
    }
    // no barrier: this wave reads only its own s_agg rows below

    // GEMM: thread owns cols j and j+64 for its wave's 8 rows.
    // Root rows read from global via wave-uniform (SGPR) pointers.
    int j = lane;
    const float4* wl0 = (const float4*)(Wl + (size_t)j * D_H);
    const float4* wl1 = (const float4*)(Wl + (size_t)(j + 64) * D_H);
    const float4* wr0 = (const float4*)(Wr + (size_t)j * D_H);
    const float4* wr1 = (const float4*)(Wr + (size_t)(j + 64) * D_H);

    const float4* xrow[RPW];
#pragma unroll
    for (int r = 0; r < RPW; r++) {
        int rowc = row0 + w * RPW + r;
        if (rowc >= N_NODES) rowc = N_NODES - 1;   // clamp; acc never written
        xrow[r] = (const float4*)(xin + (size_t)rowc * D_H);
    }

    float acc0[RPW], acc1[RPW];
#pragma unroll
    for (int r = 0; r < RPW; r++) { acc0[r] = 0.f; acc1[r] = 0.f; }

    for (int k0 = 0; k0 < D_H / 4; k0 += 2) {   // 8-scalar k-chunks
        float4 a0[2], a1[2], b0[2], b1[2];
#pragma unroll
        for (int q = 0; q < 2; q++) {
            a0[q] = wl0[k0 + q];
            a1[q] = wl1[k0 + q];
            b0[q] = wr0[k0 + q];
            b1[q] = wr1[k0 + q];
        }
#pragma unroll
        for (int r = 0; r < RPW; r++) {
            int row = w * RPW + r;
#pragma unroll
            for (int q = 0; q < 2; q++) {
                float4 xa = ((const float4*)s_agg[row])[k0 + q];
                float4 xx = xrow[r][k0 + q];
                acc0[r] += xa.x * a0[q].x + xa.y * a0[q].y + xa.z * a0[q].z + xa.w * a0[q].w
                         + xx.x * b0[q].x + xx.y * b0[q].y + xx.z * b0[q].z + xx.w * b0[q].w;
                acc1[r] += xa.x * a1[q].x + xa.y * a1[q].y + xa.z * a1[q].z + xa.w * a1[q].w
                         + xx.x * b1[q].x + xx.y * b1[q].y + xx.z * b1[q].z + xx.w * b1[q].w;
            }
        }
    }

    // BN fold
    float sc0 = gg[j] * rsqrtf(vv[j] + EPSV);
    float sh0 = bb[j] + (bl[j] - mm[j]) * sc0;
    float sc1 = gg[j + 64] * rsqrtf(vv[j + 64] + EPSV);
    float sh1 = bb[j + 64] + (bl[j + 64] - mm[j + 64]) * sc1;

    if (MODE == 0) {
#pragma unroll
        for (int r = 0; r < RPW; r++) {
            int row = row0 + w * RPW + r;
            if (row < N_NODES) {
                hout[(size_t)row * D_H + j] = fmaxf(acc0[r] * sc0 + sh0, 0.f);
                hout[(size_t)row * D_H + j + 64] = fmaxf(acc1[r] * sc1 + sh1, 0.f);
            }
        }
    } else {
        // project post-ReLU row by Wl2/Wr2 (2x128 each); wave-reduce
        float wl2_0a = Wl2[j],       wl2_0b = Wl2[j + 64];
        float wl2_1a = Wl2[128 + j], wl2_1b = Wl2[192 + j];
        float wr2_0a = Wr2[j],       wr2_0b = Wr2[j + 64];
        float wr2_1a = Wr2[128 + j], wr2_1b = Wr2[192 + j];
#pragma unroll
        for (int r = 0; r < RPW; r++) {
            float v0 = fmaxf(acc0[r] * sc0 + sh0, 0.f);
            float v1 = fmaxf(acc1[r] * sc1 + sh1, 0.f);
            float p0 = v0 * wl2_0a + v1 * wl2_0b;
            float p1 = v0 * wl2_1a + v1 * wl2_1b;
            float p2 = v0 * wr2_0a + v1 * wr2_0b;
            float p3 = v0 * wr2_1a + v1 * wr2_1b;
            for (int off = 32; off; off >>= 1) {
                p0 += __shfl_down(p0, off);
                p1 += __shfl_down(p1, off);
                p2 += __shfl_down(p2, off);
                p3 += __shfl_down(p3, off);
            }
            int row = row0 + w * RPW + r;
            if (lane == 0 && row < N_NODES)
                ((float4*)p2r2)[row] = make_float4(p0, p1, p2, p3);
        }
    }
}

// ---------------- layer-2 aggregation (2-dim) + pooling ----------------
__global__ __launch_bounds__(256) void aggpool_kernel(
    const float* __restrict__ p2r2, const int* __restrict__ row_ptr,
    const int* __restrict__ csr_src, const int* __restrict__ batch,
    const float* __restrict__ bl2,
    float* __restrict__ psum, float* __restrict__ pcnt, float* __restrict__ pmax) {
    int i = blockIdx.x * blockDim.x + threadIdx.x;
    if (i >= N_NODES) return;
    int s0 = row_ptr[i], s1 = row_ptr[i + 1];
    float a0 = 0.f, a1 = 0.f;
    int e = s0;
    for (; e + 3 < s1; e += 4) {
        float2 v0 = ((const float2*)p2r2)[(size_t)csr_src[e] * 2];
        float2 v1 = ((const float2*)p2r2)[(size_t)csr_src[e + 1] * 2];
        float2 v2 = ((const float2*)p2r2)[(size_t)csr_src[e + 2] * 2];
        float2 v3 = ((const float2*)p2r2)[(size_t)csr_src[e + 3] * 2];
        a0 += (v0.x + v1.x) + (v2.x + v3.x);
        a1 += (v0.y + v1.y) + (v2.y + v3.y);
    }
    for (; e < s1; e++) {
        float2 v = ((const float2*)p2r2)[(size_t)csr_src[e] * 2];
        a0 += v.x;
        a1 += v.y;
    }
    float inv = 1.0f / (float)max(s1 - s0, 1);
    float2 r = ((const float2*)p2r2)[(size_t)i * 2 + 1];
    float h0 = a0 * inv + bl2[0] + r.x;
    float h1 = a1 * inv + bl2[1] + r.y;
    int b = batch[i];
    atomicAdd(&psum[b * 2], h0);
    atomicAdd(&psum[b * 2 + 1], h1);
    atomicAdd(&pcnt[b], 1.0f);
    atomicMaxF(&pmax[b * 2], h0);
    atomicMaxF(&pmax[b * 2 + 1], h1);
}

// ---------------- graph MLP ----------------
__global__ __launch_bounds__(128) void mlp_kernel(
    const float* __restrict__ psum, const float* __restrict__ pcnt,
    const float* __restrict__ pmax,
    const float* __restrict__ mW1, const float* __restrict__ mb1,
    const float* __restrict__ mW2, const float* __restrict__ mb2,
    float* __restrict__ out) {
    int b = blockIdx.x;
    int t = threadIdx.x;
    float cntv = fmaxf(pcnt[b], 1.0f);
    float g0 = psum[b * 2] / cntv;
    float g1 = psum[b * 2 + 1] / cntv;
    float g2 = pmax[b * 2];
    float g3 = pmax[b * 2 + 1];
    float4 w = ((const float4*)mW1)[t];
    float h = fmaxf(g0 * w.x + g1 * w.y + g2 * w.z + g3 * w.w + mb1[t], 0.f);
    float o0 = h * mW2[t];
    float o1 = h * mW2[128 + t];
    for (int off = 32; off; off >>= 1) {
        o0 += __shfl_down(o0, off);
        o1 += __shfl_down(o1, off);
    }
    __shared__ float sh[4];
    if ((t & 63) == 0) {
        sh[(t >> 6) * 2] = o0;
        sh[(t >> 6) * 2 + 1] = o1;
    }
    __syncthreads();
    if (t == 0) {
        out[b * 2] = sh[0] + sh[2] + mb2[0];
        out[b * 2 + 1] = sh[1] + sh[3] + mb2[1];
    }
}

extern "C" void kernel_launch(void* const* d_in, const int* in_sizes, int n_in,
                              void* d_out, int out_size, void* d_ws, size_t ws_size,
                              hipStream_t stream) {
    const float* x = (const float*)d_in[0];
    const int* ei = (const int*)d_in[1];
    const int* batch = (const int*)d_in[2];
    const float* Wl0 = (const float*)d_in[3];
    const float* bl0 = (const float*)d_in[4];
    const float* Wr0 = (const float*)d_in[5];
    const float* Wl1 = (const float*)d_in[6];
    const float* bl1 = (const float*)d_in[7];
    const float* Wr1 = (const float*)d_in[8];
    const float* Wl2 = (const float*)d_in[9];
    const float* bl2 = (const float*)d_in[10];
    const float* Wr2 = (const float*)d_in[11];
    const float* g0 = (const float*)d_in[12];
    const float* b0 = (const float*)d_in[13];
    const float* m0 = (const float*)d_in[14];
    const float* v0 = (const float*)d_in[15];
    const float* g1 = (const float*)d_in[16];
    const float* b1 = (const float*)d_in[17];
    const float* m1 = (const float*)d_in[18];
    const float* v1 = (const float*)d_in[19];
    const float* mW1 = (const float*)d_in[20];
    const float* mb1 = (const float*)d_in[21];
    const float* mW2 = (const float*)d_in[22];
    const float* mb2 = (const float*)d_in[23];

    const int* src = ei;
    const int* dst = ei + N_EDGES;

    // workspace layout — total ~28.8 MB (overflow corrupts harness memory)
    char* ws = (char*)d_ws;
    size_t off = 0;
    auto alloc = [&](size_t bytes) -> char* {
        char* p = ws + off;
        off += (bytes + 255) & ~(size_t)255;
        return p;
    };
    int* cnt = (int*)alloc((size_t)N_NODES * 4);
    int* row_ptr = (int*)alloc((size_t)(N_NODES + 1) * 4);
    int* wofs = (int*)alloc((size_t)N_NODES * 4);
    int* csr_src = (int*)alloc((size_t)N_EDGES * 4);
    float* h0 = (float*)alloc((size_t)N_NODES * D_H * 4);
    float* p2r2 = (float*)alloc((size_t)N_NODES * 16);
    float* psum = (float*)alloc((size_t)N_GRAPHS * 2 * 4);
    float* pcnt = (float*)alloc((size_t)N_GRAPHS * 4);
    float* pmax = (float*)alloc((size_t)N_GRAPHS * 2 * 4);
    int* bsum = (int*)alloc((size_t)NB_SCAN * 4);
    (void)ws_size;

    // CSR build
    hipMemsetAsync(cnt, 0, (size_t)N_NODES * 4, stream);
    hist_kernel<<<(N_EDGES + 255) / 256, 256, 0, stream>>>(dst, cnt);
    scan_local_kernel<<<NB_SCAN, 256, 0, stream>>>(cnt, row_ptr, bsum);
    scan_add_kernel<<<NB_SCAN, 256, 0, stream>>>(row_ptr, wofs, bsum, psum, pcnt, pmax);
    scatter_kernel<<<(N_EDGES + 255) / 256, 256, 0, stream>>>(src, dst, wofs, csr_src);

    int nblk = (N_NODES + ROWS - 1) / ROWS;

    // layer 0: gather(x) + gemm + BN + ReLU -> h0
    fused_sage_kernel<0><<<nblk, 256, 0, stream>>>(
        x, row_ptr, csr_src, Wl0, bl0, Wr0, g0, b0, m0, v0, h0,
        nullptr, nullptr, nullptr);

    // layer 1: gather(h0) + gemm + BN + ReLU + project-by-(Wl2,Wr2) -> p2r2
    fused_sage_kernel<1><<<nblk, 256, 0, stream>>>(
        h0, row_ptr, csr_src, Wl1, bl1, Wr1, g1, b1, m1, v1, nullptr,
        Wl2, Wr2, p2r2);

    // pooling (pools pre-initialized in scan_add_kernel)
    aggpool_kernel<<<(N_NODES + 255) / 256, 256, 0, stream>>>(
        p2r2, row_ptr, csr_src, batch, bl2, psum, pcnt, pmax);

    // graph MLP
    mlp_kernel<<<N_GRAPHS, 128, 0, stream>>>(psum, pcnt, pmax, mW1, mb1, mW2, mb2,
                                             (float*)d_out);
}

// Round 12
// 586.917 us; speedup vs baseline: 2.5560x; 2.5560x over previous
//
#include <hip/hip_runtime.h>
#include <hip/hip_bf16.h>
#include <float.h>

#define N_NODES 50000
#define N_EDGES 800000
#define D_H 128
#define N_GRAPHS 512
#define EPSV 1e-5f
#define NB_SCAN ((N_NODES + 255) / 256)   // 196

// ---------------- atomic float max (bit trick) ----------------
__device__ __forceinline__ void atomicMaxF(float* addr, float val) {
    if (val >= 0.0f) atomicMax((int*)addr, __float_as_int(val));
    else atomicMin((unsigned int*)addr, (unsigned int)__float_as_int(val));
}

// ---------------- CSR build ----------------
__global__ void hist_kernel(const int* __restrict__ dst, int* __restrict__ cnt) {
    int e = blockIdx.x * blockDim.x + threadIdx.x;
    if (e < N_EDGES) atomicAdd(&cnt[dst[e]], 1);
}

__global__ __launch_bounds__(256) void scan_local_kernel(const int* __restrict__ cnt,
                                                         int* __restrict__ row_ptr,
                                                         int* __restrict__ bsum) {
    __shared__ int sh[256];
    int t = threadIdx.x;
    int i = blockIdx.x * 256 + t;
    int v = (i < N_NODES) ? cnt[i] : 0;
    sh[t] = v;
    __syncthreads();
    int x = v;
    for (int off = 1; off < 256; off <<= 1) {
        int y = (t >= off) ? sh[t - off] : 0;
        __syncthreads();
        x += y;
        sh[t] = x;
        __syncthreads();
    }
    if (i < N_NODES) row_ptr[i] = x - v;   // local exclusive
    if (t == 255) bsum[blockIdx.x] = x;
}

// add block offsets (each block reduces bsum itself); init pools + row_ptr[N]
__global__ __launch_bounds__(256) void scan_add_kernel(int* __restrict__ row_ptr,
                                                       int* __restrict__ wofs,
                                                       const int* __restrict__ bsum,
                                                       float* __restrict__ psum,
                                                       float* __restrict__ pcnt,
                                                       float* __restrict__ pmax) {
    __shared__ int sh[256];
    int t = threadIdx.x;
    int v = (t < NB_SCAN && t < blockIdx.x) ? bsum[t] : 0;
    sh[t] = v;
    __syncthreads();
    for (int off = 128; off; off >>= 1) {
        if (t < off) sh[t] += sh[t + off];
        __syncthreads();
    }
    int bofs = sh[0];
    int i = blockIdx.x * 256 + t;
    if (i < N_NODES) {
        int r = row_ptr[i] + bofs;
        row_ptr[i] = r;
        wofs[i] = r;
    }
    if (i == 0) row_ptr[N_NODES] = N_EDGES;
    if (i < N_GRAPHS * 2) { psum[i] = 0.f; pmax[i] = -FLT_MAX; }
    if (i < N_GRAPHS) pcnt[i] = 0.f;
}

__global__ void scatter_kernel(const int* __restrict__ src, const int* __restrict__ dst,
                               int* __restrict__ wofs, int* __restrict__ csr_src) {
    int e = blockIdx.x * blockDim.x + threadIdx.x;
    if (e < N_EDGES) {
        int pos = atomicAdd(&wofs[dst[e]], 1);
        csr_src[pos] = src[e];
    }
}

// ---------------- fused SAGE layer: pipelined gather + GEMM + BN + ReLU -------
// 4 waves/block of 256; wave owns RPW=8 rows end-to-end; LDS rows wave-private
// -> NO barrier. KEY: indices are fetched 64-at-a-time in ONE coalesced wave
// load and extracted via __shfl (ds_bpermute -> lgkmcnt), so row-load vmcnt
// waits never entangle with index loads. Steady state: vmcnt(8)-style waits,
// next chunk of 8 row loads always in flight, idx load 7 chunks ahead.
// launch_bounds(256,4): 128-VGPR budget -> clean 64-80 VGPR codegen.
// NEVER use min-waves>=6 here: compiler collapses to 40 VGPR + 1GB spill (R6/R11).
#define ROWS 32
#define RPW 8   // rows per wave
template <int MODE>
__global__ __launch_bounds__(256, 4) void fused_sage_kernel(
    const float* __restrict__ xin,
    const int* __restrict__ row_ptr, const int* __restrict__ csr_src,
    const float* __restrict__ Wl, const float* __restrict__ bl,
    const float* __restrict__ Wr,
    const float* __restrict__ gg, const float* __restrict__ bb,
    const float* __restrict__ mm, const float* __restrict__ vv,
    float* __restrict__ hout,
    const float* __restrict__ Wl2, const float* __restrict__ Wr2,
    float* __restrict__ p2r2) {
    __shared__ float s_agg[ROWS][D_H];
    __shared__ float s_x[ROWS][D_H];
    int row0 = blockIdx.x * ROWS;
    int t = threadIdx.x;
    int lane = t & 63;
    int w = t >> 6;   // wave id 0..3

    const float2* xp = (const float2*)xin;

    // stage root rows (wave-private, 1 float2/lane/row)
#pragma unroll
    for (int rr = 0; rr < RPW; rr++) {
        int r = w * RPW + rr;
        int row = row0 + r;
        float2 vx = make_float2(0.f, 0.f);
        if (row < N_NODES) vx = xp[(size_t)row * 64 + lane];
        ((float2*)s_x[r])[lane] = vx;
    }

    // pipelined gather over the wave's contiguous edge range
    int rbeg = row0 + w * RPW;
    int rwend = rbeg + RPW; if (rwend > N_NODES) rwend = N_NODES;
    if (rbeg < N_NODES) {
        int E0 = row_ptr[rbeg];
        int E1 = row_ptr[rwend];
        int cur = rbeg;
        int cur_start = E0;
        int cur_end = row_ptr[cur + 1];
        float ax = 0.f, ay = 0.f;

        float2 vA[8], vB[8];

        // one coalesced wave load: 64 indices (superchunk)
        auto loadIdx = [&](int sb) -> int {
            int e = sb + lane;
            return csr_src[(e < E1) ? e : (E1 - 1)];
        };
        // extract 8 indices from the superchunk reg via shfl (lgkmcnt path)
        auto rowLoadShfl = [&](float2* V, int idxreg, int off) {
#pragma unroll
            for (int k = 0; k < 8; k++) {
                int sidx = __shfl(idxreg, off + k);
                V[k] = xp[(size_t)sidx * 64 + lane];
            }
        };
        auto consume = [&](const float2* V, int cbase) {
#pragma unroll
            for (int k = 0; k < 8; k++) {
                int epos = cbase + k;
                if (epos < E1) {
                    while (epos >= cur_end) {   // finalize rows (handles empties)
                        float inv = 1.0f / (float)max(cur_end - cur_start, 1);
                        ((float2*)s_agg[cur - row0])[lane] =
                            make_float2(ax * inv, ay * inv);
                        ax = 0.f; ay = 0.f;
                        cur++;
                        cur_start = cur_end;
                        cur_end = row_ptr[cur + 1];
                    }
                    ax += V[k].x;
                    ay += V[k].y;
                }
            }
        };

        int nch = (E1 - E0 + 7) >> 3;   // 8-edge chunks
        if (nch > 0) {
            int iC = loadIdx(E0);       // superchunk 0 (chunks 0..7)
            int iN = iC;
            rowLoadShfl(vA, iC, 0);     // chunk 0 rows (prologue idx-wait only)
            for (int c = 0; c < nch; c++) {
                int base = E0 + c * 8;
                // issue next superchunk's idx early (7 chunks of latency cover)
                if ((c & 7) == 0 && c + 8 < nch) iN = loadIdx(base + 64);
                // prefetch rows for chunk c+1
                if (c + 1 < nch) {
                    int nwi = (c + 1) & 7;
                    int reg = (nwi == 0) ? iN : iC;
                    if (c & 1) rowLoadShfl(vA, reg, nwi * 8);
                    else       rowLoadShfl(vB, reg, nwi * 8);
                }
                // consume chunk c
                if (c & 1) consume(vB, base);
                else       consume(vA, base);
                if (((c + 1) & 7) == 0) iC = iN;   // superchunk rotate
            }
        }
        // drain remaining rows (partial current + trailing empties)
        while (cur < rwend) {
            float inv = 1.0f / (float)max(cur_end - cur_start, 1);
            ((float2*)s_agg[cur - row0])[lane] = make_float2(ax * inv, ay * inv);
            ax = 0.f; ay = 0.f;
            cur++;
            if (cur < rwend) { cur_start = cur_end; cur_end = row_ptr[cur + 1]; }
        }
    }
    // no barrier: this wave reads only its own rows below

    // GEMM: thread owns cols j and j+64 for its wave's 8 rows
    int j = lane;
    const float4* wl0 = (const float4*)(Wl + (size_t)j * D_H);
    const float4* wl1 = (const float4*)(Wl + (size_t)(j + 64) * D_H);
    const float4* wr0 = (const float4*)(Wr + (size_t)j * D_H);
    const float4* wr1 = (const float4*)(Wr + (size_t)(j + 64) * D_H);

    float acc0[RPW], acc1[RPW];
#pragma unroll
    for (int r = 0; r < RPW; r++) { acc0[r] = 0.f; acc1[r] = 0.f; }

    for (int k0 = 0; k0 < D_H / 4; k0 += 2) {   // 8-scalar k-chunks
        float4 a0[2], a1[2], b0[2], b1[2];
#pragma unroll
        for (int q = 0; q < 2; q++) {
            a0[q] = wl0[k0 + q];
            a1[q] = wl1[k0 + q];
            b0[q] = wr0[k0 + q];
            b1[q] = wr1[k0 + q];
        }
#pragma unroll
        for (int r = 0; r < RPW; r++) {
            int row = w * RPW + r;
#pragma unroll
            for (int q = 0; q < 2; q++) {
                float4 xa = ((const float4*)s_agg[row])[k0 + q];
                float4 xx = ((const float4*)s_x[row])[k0 + q];
                acc0[r] += xa.x * a0[q].x + xa.y * a0[q].y + xa.z * a0[q].z + xa.w * a0[q].w
                         + xx.x * b0[q].x + xx.y * b0[q].y + xx.z * b0[q].z + xx.w * b0[q].w;
                acc1[r] += xa.x * a1[q].x + xa.y * a1[q].y + xa.z * a1[q].z + xa.w * a1[q].w
                         + xx.x * b1[q].x + xx.y * b1[q].y + xx.z * b1[q].z + xx.w * b1[q].w;
            }
        }
    }

    // BN fold
    float sc0 = gg[j] * rsqrtf(vv[j] + EPSV);
    float sh0 = bb[j] + (bl[j] - mm[j]) * sc0;
    float sc1 = gg[j + 64] * rsqrtf(vv[j + 64] + EPSV);
    float sh1 = bb[j + 64] + (bl[j + 64] - mm[j + 64]) * sc1;

    if (MODE == 0) {
#pragma unroll
        for (int r = 0; r < RPW; r++) {
            int row = row0 + w * RPW + r;
            if (row < N_NODES) {
                hout[(size_t)row * D_H + j] = fmaxf(acc0[r] * sc0 + sh0, 0.f);
                hout[(size_t)row * D_H + j + 64] = fmaxf(acc1[r] * sc1 + sh1, 0.f);
            }
        }
    } else {
        // project post-ReLU row by Wl2/Wr2 (2x128 each); wave-reduce
        float wl2_0a = Wl2[j],       wl2_0b = Wl2[j + 64];
        float wl2_1a = Wl2[128 + j], wl2_1b = Wl2[192 + j];
        float wr2_0a = Wr2[j],       wr2_0b = Wr2[j + 64];
        float wr2_1a = Wr2[128 + j], wr2_1b = Wr2[192 + j];
#pragma unroll
        for (int r = 0; r < RPW; r++) {
            float v0 = fmaxf(acc0[r] * sc0 + sh0, 0.f);
            float v1 = fmaxf(acc1[r] * sc1 + sh1, 0.f);
            float p0 = v0 * wl2_0a + v1 * wl2_0b;
            float p1 = v0 * wl2_1a + v1 * wl2_1b;
            float p2 = v0 * wr2_0a + v1 * wr2_0b;
            float p3 = v0 * wr2_1a + v1 * wr2_1b;
            for (int off = 32; off; off >>= 1) {
                p0 += __shfl_down(p0, off);
                p1 += __shfl_down(p1, off);
                p2 += __shfl_down(p2, off);
                p3 += __shfl_down(p3, off);
            }
            int row = row0 + w * RPW + r;
            if (lane == 0 && row < N_NODES)
                ((float4*)p2r2)[row] = make_float4(p0, p1, p2, p3);
        }
    }
}

// ---------------- layer-2 aggregation (2-dim) + pooling ----------------
__global__ __launch_bounds__(256) void aggpool_kernel(
    const float* __restrict__ p2r2, const int* __restrict__ row_ptr,
    const int* __restrict__ csr_src, const int* __restrict__ batch,
    const float* __restrict__ bl2,
    float* __restrict__ psum, float* __restrict__ pcnt, float* __restrict__ pmax) {
    int i = blockIdx.x * blockDim.x + threadIdx.x;
    if (i >= N_NODES) return;
    int s0 = row_ptr[i], s1 = row_ptr[i + 1];
    float a0 = 0.f, a1 = 0.f;
    int e = s0;
    for (; e + 3 < s1; e += 4) {
        float2 v0 = ((const float2*)p2r2)[(size_t)csr_src[e] * 2];
        float2 v1 = ((const float2*)p2r2)[(size_t)csr_src[e + 1] * 2];
        float2 v2 = ((const float2*)p2r2)[(size_t)csr_src[e + 2] * 2];
        float2 v3 = ((const float2*)p2r2)[(size_t)csr_src[e + 3] * 2];
        a0 += (v0.x + v1.x) + (v2.x + v3.x);
        a1 += (v0.y + v1.y) + (v2.y + v3.y);
    }
    for (; e < s1; e++) {
        float2 v = ((const float2*)p2r2)[(size_t)csr_src[e] * 2];
        a0 += v.x;
        a1 += v.y;
    }
    float inv = 1.0f / (float)max(s1 - s0, 1);
    float2 r = ((const float2*)p2r2)[(size_t)i * 2 + 1];
    float h0 = a0 * inv + bl2[0] + r.x;
    float h1 = a1 * inv + bl2[1] + r.y;
    int b = batch[i];
    atomicAdd(&psum[b * 2], h0);
    atomicAdd(&psum[b * 2 + 1], h1);
    atomicAdd(&pcnt[b], 1.0f);
    atomicMaxF(&pmax[b * 2], h0);
    atomicMaxF(&pmax[b * 2 + 1], h1);
}

// ---------------- graph MLP ----------------
__global__ __launch_bounds__(128) void mlp_kernel(
    const float* __restrict__ psum, const float* __restrict__ pcnt,
    const float* __restrict__ pmax,
    const float* __restrict__ mW1, const float* __restrict__ mb1,
    const float* __restrict__ mW2, const float* __restrict__ mb2,
    float* __restrict__ out) {
    int b = blockIdx.x;
    int t = threadIdx.x;
    float cntv = fmaxf(pcnt[b], 1.0f);
    float g0 = psum[b * 2] / cntv;
    float g1 = psum[b * 2 + 1] / cntv;
    float g2 = pmax[b * 2];
    float g3 = pmax[b * 2 + 1];
    float4 w = ((const float4*)mW1)[t];
    float h = fmaxf(g0 * w.x + g1 * w.y + g2 * w.z + g3 * w.w + mb1[t], 0.f);
    float o0 = h * mW2[t];
    float o1 = h * mW2[128 + t];
    for (int off = 32; off; off >>= 1) {
        o0 += __shfl_down(o0, off);
        o1 += __shfl_down(o1, off);
    }
    __shared__ float sh[4];
    if ((t & 63) == 0) {
        sh[(t >> 6) * 2] = o0;
        sh[(t >> 6) * 2 + 1] = o1;
    }
    __syncthreads();
    if (t == 0) {
        out[b * 2] = sh[0] + sh[2] + mb2[0];
        out[b * 2 + 1] = sh[1] + sh[3] + mb2[1];
    }
}

extern "C" void kernel_launch(void* const* d_in, const int* in_sizes, int n_in,
                              void* d_out, int out_size, void* d_ws, size_t ws_size,
                              hipStream_t stream) {
    const float* x = (const float*)d_in[0];
    const int* ei = (const int*)d_in[1];
    const int* batch = (const int*)d_in[2];
    const float* Wl0 = (const float*)d_in[3];
    const float* bl0 = (const float*)d_in[4];
    const float* Wr0 = (const float*)d_in[5];
    const float* Wl1 = (const float*)d_in[6];
    const float* bl1 = (const float*)d_in[7];
    const float* Wr1 = (const float*)d_in[8];
    const float* Wl2 = (const float*)d_in[9];
    const float* bl2 = (const float*)d_in[10];
    const float* Wr2 = (const float*)d_in[11];
    const float* g0 = (const float*)d_in[12];
    const float* b0 = (const float*)d_in[13];
    const float* m0 = (const float*)d_in[14];
    const float* v0 = (const float*)d_in[15];
    const float* g1 = (const float*)d_in[16];
    const float* b1 = (const float*)d_in[17];
    const float* m1 = (const float*)d_in[18];
    const float* v1 = (const float*)d_in[19];
    const float* mW1 = (const float*)d_in[20];
    const float* mb1 = (const float*)d_in[21];
    const float* mW2 = (const float*)d_in[22];
    const float* mb2 = (const float*)d_in[23];

    const int* src = ei;
    const int* dst = ei + N_EDGES;

    // workspace layout — total ~28.8 MB (overflow corrupts harness memory)
    char* ws = (char*)d_ws;
    size_t off = 0;
    auto alloc = [&](size_t bytes) -> char* {
        char* p = ws + off;
        off += (bytes + 255) & ~(size_t)255;
        return p;
    };
    int* cnt = (int*)alloc((size_t)N_NODES * 4);
    int* row_ptr = (int*)alloc((size_t)(N_NODES + 1) * 4);
    int* wofs = (int*)alloc((size_t)N_NODES * 4);
    int* csr_src = (int*)alloc((size_t)N_EDGES * 4);
    float* h0 = (float*)alloc((size_t)N_NODES * D_H * 4);
    float* p2r2 = (float*)alloc((size_t)N_NODES * 16);
    float* psum = (float*)alloc((size_t)N_GRAPHS * 2 * 4);
    float* pcnt = (float*)alloc((size_t)N_GRAPHS * 4);
    float* pmax = (float*)alloc((size_t)N_GRAPHS * 2 * 4);
    int* bsum = (int*)alloc((size_t)NB_SCAN * 4);
    (void)ws_size;

    // CSR build
    hipMemsetAsync(cnt, 0, (size_t)N_NODES * 4, stream);
    hist_kernel<<<(N_EDGES + 255) / 256, 256, 0, stream>>>(dst, cnt);
    scan_local_kernel<<<NB_SCAN, 256, 0, stream>>>(cnt, row_ptr, bsum);
    scan_add_kernel<<<NB_SCAN, 256, 0, stream>>>(row_ptr, wofs, bsum, psum, pcnt, pmax);
    scatter_kernel<<<(N_EDGES + 255) / 256, 256, 0, stream>>>(src, dst, wofs, csr_src);

    int nblk = (N_NODES + ROWS - 1) / ROWS;

    // layer 0: gather(x) + gemm + BN + ReLU -> h0
    fused_sage_kernel<0><<<nblk, 256, 0, stream>>>(
        x, row_ptr, csr_src, Wl0, bl0, Wr0, g0, b0, m0, v0, h0,
        nullptr, nullptr, nullptr);

    // layer 1: gather(h0) + gemm + BN + ReLU + project-by-(Wl2,Wr2) -> p2r2
    fused_sage_kernel<1><<<nblk, 256, 0, stream>>>(
        h0, row_ptr, csr_src, Wl1, bl1, Wr1, g1, b1, m1, v1, nullptr,
        Wl2, Wr2, p2r2);

    // pooling (pools pre-initialized in scan_add_kernel)
    aggpool_kernel<<<(N_NODES + 255) / 256, 256, 0, stream>>>(
        p2r2, row_ptr, csr_src, batch, bl2, psum, pcnt, pmax);

    // graph MLP
    mlp_kernel<<<N_GRAPHS, 128, 0, stream>>>(psum, pcnt, pmax, mW1, mb1, mW2, mb2,
                                             (float*)d_out);
}